// Round 3
// baseline (905.248 us; speedup 1.0000x reference)
//
#include <hip/hip_runtime.h>
#include <cstdint>
#include <cstddef>

// ---------------- open-addressing hash params (dup/fallback authority) ----------------
#define OA_LOG 21
static constexpr unsigned OA_SLOTS = 1u << OA_LOG;   // 2M slots x 8B = 16 MB, load ~0.5
static constexpr unsigned OA_MASK  = OA_SLOTS - 1;
static constexpr unsigned HASH_MUL = 2654435761u;    // Knuth multiplicative
static constexpr unsigned GSZ = 400;                 // nodes per graph (key compressor only;
                                                     // violations fall back to OA path)
static constexpr unsigned DENSE_DUP = 0xFFFFFFFFu;

typedef __attribute__((ext_vector_type(8))) short short8;   // 8 bf16 (4 VGPRs)
typedef __attribute__((ext_vector_type(4))) float floatx4;  // MFMA C/D

union U4S8 { uint4 u; short8 s; };

__device__ inline unsigned bf16rn(float x) {                // RNE f32->bf16
    unsigned u = __float_as_uint(x);
    return (u + 0x7FFFu + ((u >> 16) & 1u)) >> 16;
}
__device__ inline unsigned pk2(float a, float b) {
    return bf16rn(a) | (bf16rn(b) << 16);
}

// ---- pack W (128x64 f32, row-major) into 16 MFMA B-fragments of bf16 ----
__global__ void wpack_kernel(const float* __restrict__ W, uint4* __restrict__ wsW) {
    const int lane = threadIdx.x;   // 64 threads
    const int n = lane & 15, q = lane >> 4;
    for (int s = 0; s < 4; ++s)
        for (int t = 0; t < 4; ++t) {
            unsigned dw[4];
#pragma unroll
            for (int jj = 0; jj < 4; ++jj) {
                float a = W[(32 * s + 8 * q + 2 * jj) * 64 + 16 * t + n];
                float b = W[(32 * s + 8 * q + 2 * jj + 1) * 64 + 16 * t + n];
                dw[jj] = pk2(a, b);
            }
            wsW[(s * 4 + t) * 64 + lane] = make_uint4(dw[0], dw[1], dw[2], dw[3]);
        }
}

// ---- fused prep: histogram + OA insert + dense index build (one edge pass) ----
__global__ void prep_build_kernel(const int* __restrict__ esrc,
                                  const int* __restrict__ edst,
                                  int* __restrict__ cnt,
                                  unsigned long long* __restrict__ tbl,
                                  unsigned* __restrict__ dense,   // may be null
                                  int E, unsigned NN) {
    int e = blockIdx.x * blockDim.x + threadIdx.x;
    if (e >= E) return;
    const unsigned s = (unsigned)esrc[e], d = (unsigned)edst[e];
    atomicAdd(&cnt[d], 1);

    unsigned k = s * NN + d;                       // global key, < 2^31
    unsigned long long mine = ((unsigned long long)(unsigned)e << 32) | (unsigned long long)k;
    unsigned slot = (k * HASH_MUL) >> (32 - OA_LOG);
    const unsigned long long EMPTY = ~0ull;
    while (atomicCAS(&tbl[slot], EMPTY, mine) != EMPTY)
        slot = (slot + 1) & OA_MASK;

    if (dense) {
        const unsigned gs = s / GSZ, gd = d / GSZ;
        if (gs == gd) {                            // dense-eligible (within-graph pair)
            unsigned dk = s * GSZ + (d - gd * GSZ);
            unsigned old = atomicCAS(&dense[dk], 0u, (unsigned)e + 1u);
            if (old != 0u) atomicExch(&dense[dk], DENSE_DUP);
        }
    }
}

// one block, 1024 threads; exclusive offsets -> off[], cnt[] becomes scatter cursor
__global__ void scan_kernel(int* __restrict__ cnt, int* __restrict__ off, int NN, int E) {
    __shared__ int sd[1024];
    const int t = threadIdx.x;
    const int chunk = (NN + 1023) >> 10;
    const int lo = t * chunk, hi = min(lo + chunk, NN);
    int local = 0;
    for (int i = lo; i < hi; ++i) local += cnt[i];
    sd[t] = local;
    __syncthreads();
    for (int s = 1; s < 1024; s <<= 1) {
        int v = (t >= s) ? sd[t - s] : 0;
        __syncthreads();
        sd[t] += v;
        __syncthreads();
    }
    int run = sd[t] - local;  // exclusive base
    for (int i = lo; i < hi; ++i) {
        int c = cnt[i];
        off[i] = run;
        cnt[i] = run;   // cursor
        run += c;
    }
    if (t == 0) off[NN] = E;
}

__global__ void scatter_kernel(const int* __restrict__ edst, int* __restrict__ cursor,
                               int* __restrict__ csr, int E) {
    int e = blockIdx.x * blockDim.x + threadIdx.x;
    if (e >= E) return;
    int slot = atomicAdd(&cursor[edst[e]], 1);
    csr[slot] = e;
}

// ---- fallback only (small workspace): revid from OA table ----
__global__ void mark_rev_kernel(const int* __restrict__ esrc,
                                const int* __restrict__ edst,
                                const unsigned long long* __restrict__ tbl,
                                int* __restrict__ revid,
                                int E, unsigned NN) {
    int e = blockIdx.x * blockDim.x + threadIdx.x;
    if (e >= E) return;
    unsigned rk = (unsigned)edst[e] * NN + (unsigned)esrc[e];
    unsigned s = (rk * HASH_MUL) >> (32 - OA_LOG);
    int cnt = 0, idx = -1;
    while (true) {
        unsigned long long v = tbl[s];
        if ((unsigned)v == 0xFFFFFFFFu) break;
        if ((unsigned)v == rk) { ++cnt; idx = (int)(v >> 32); }
        s = (s + 1) & OA_MASK;
    }
    revid[e] = (cnt == 1) ? idx : -1;
}

// ---- agg via CSR: one wave per node, lane = column; 8-deep load pipelining ----
__global__ __launch_bounds__(256)
void agg_csr_kernel(const float* __restrict__ feat, const int* __restrict__ csr,
                    const int* __restrict__ off, float* __restrict__ agg, int NN) {
    const int wid = (blockIdx.x * blockDim.x + threadIdx.x) >> 6;
    const int lane = threadIdx.x & 63;
    if (wid >= NN) return;
    const int i0 = off[wid], i1 = off[wid + 1];
    float acc = 0.f;
    int i = i0;
    for (; i + 8 <= i1; i += 8) {
        int c[8];
#pragma unroll
        for (int j = 0; j < 8; ++j) c[j] = csr[i + j];
        float a[8];
#pragma unroll
        for (int j = 0; j < 8; ++j) a[j] = feat[((long long)c[j] << 6) + lane];
        acc += ((a[0] + a[1]) + (a[2] + a[3])) + ((a[4] + a[5]) + (a[6] + a[7]));
    }
    for (; i < i1; ++i) acc += feat[((long long)csr[i] << 6) + lane];
    agg[((long long)wid << 6) + lane] = acc;
}

// ---- fused: h = [feat, agg[src]-revsum] (bf16, LDS) ; out = relu(h@W + b) via MFMA ----
__global__ __launch_bounds__(256, 4)
void fused_kernel(const float* __restrict__ feat,
                  const int* __restrict__ esrc,
                  const int* __restrict__ edst,
                  const float* __restrict__ agg,
                  const unsigned long long* __restrict__ tbl,
                  const unsigned* __restrict__ dense,   // dense index (preferred)
                  const int* __restrict__ revid,        // fallback
                  int use_dense,
                  const uint4* __restrict__ wsW,
                  const float* __restrict__ bias,
                  float* __restrict__ out,
                  int E, unsigned NN) {
    // 64 edge rows x 128 bf16 cols, padded to 68 dwords/row
    __shared__ unsigned lds_h[64 * 68];
    const int tid = threadIdx.x;
    const int lane = tid & 63;
    const int n = lane & 15;
    const int q = lane >> 4;
    const int g = blockIdx.x;
    const long long H = (long long)(E >> 1);
    const bool paired = (E & 63) == 0;

    // ---- phase 1: 4 threads/edge, 16 cols each ----
    const int el = tid >> 2;     // LDS row 0..63
    const int p = tid & 3;
    long long e;
    if (paired) e = (long long)g * 32 + (el & 31) + (long long)(el >> 5) * H;
    else        e = (long long)g * 64 + el;

    float4 f0, f1, f2, f3, m0, m1, m2, m3;
    if (e < (long long)E) {
        const float4* fp = (const float4*)(feat + (e << 6) + 16 * p);
        f0 = fp[0]; f1 = fp[1]; f2 = fp[2]; f3 = fp[3];
        const int s_ = esrc[e], d_ = edst[e];
        const float4* ap = (const float4*)(agg + ((long long)s_ << 6) + 16 * p);
        m0 = ap[0]; m1 = ap[1]; m2 = ap[2]; m3 = ap[3];

        // resolve reverse-edge group
        int rid = -1;
        bool slow = false;
        if (use_dense) {
            const unsigned gs = (unsigned)s_ / GSZ, gd = (unsigned)d_ / GSZ;
            if (gs == gd) {
                unsigned v = dense[(unsigned)d_ * GSZ + ((unsigned)s_ - gs * GSZ)];
                if (v == 0u) { /* no reverse edge: rev = 0 */ }
                else if (v == DENSE_DUP) slow = true;
                else rid = (int)(v - 1u);
            } else slow = true;
        } else {
            rid = revid[e];
            if (rid < 0) slow = true;
        }

        float4 r0, r1, r2, r3;
        r0 = r1 = r2 = r3 = make_float4(0.f, 0.f, 0.f, 0.f);
        if (rid >= 0) {
            // fast path: unique reverse edge; row is L1-hot (partner group in
            // this block loads it as its self row under the paired layout)
            const float4* rp = (const float4*)(feat + ((long long)rid << 6) + 16 * p);
            r0 = rp[0]; r1 = rp[1]; r2 = rp[2]; r3 = rp[3];
        } else if (slow) {
            // slow path: OA probe, sum ALL matches (multi-edges); 0 if none
            const unsigned rk = (unsigned)d_ * NN + (unsigned)s_;
            unsigned slot = (rk * HASH_MUL) >> (32 - OA_LOG);
            while (true) {
                unsigned long long v = tbl[slot];
                if ((unsigned)v == 0xFFFFFFFFu) break;
                if ((unsigned)v == rk) {
                    const float4* rp =
                        (const float4*)(feat + ((long long)(v >> 32) << 6) + 16 * p);
                    float4 a0 = rp[0], a1 = rp[1], a2 = rp[2], a3 = rp[3];
                    r0.x += a0.x; r0.y += a0.y; r0.z += a0.z; r0.w += a0.w;
                    r1.x += a1.x; r1.y += a1.y; r1.z += a1.z; r1.w += a1.w;
                    r2.x += a2.x; r2.y += a2.y; r2.z += a2.z; r2.w += a2.w;
                    r3.x += a3.x; r3.y += a3.y; r3.z += a3.z; r3.w += a3.w;
                }
                slot = (slot + 1) & OA_MASK;
            }
        }
        m0.x -= r0.x; m0.y -= r0.y; m0.z -= r0.z; m0.w -= r0.w;
        m1.x -= r1.x; m1.y -= r1.y; m1.z -= r1.z; m1.w -= r1.w;
        m2.x -= r2.x; m2.y -= r2.y; m2.z -= r2.z; m2.w -= r2.w;
        m3.x -= r3.x; m3.y -= r3.y; m3.z -= r3.z; m3.w -= r3.w;
    } else {
        f0 = f1 = f2 = f3 = make_float4(0.f, 0.f, 0.f, 0.f);
        m0 = m1 = m2 = m3 = make_float4(0.f, 0.f, 0.f, 0.f);
    }
    unsigned* row = &lds_h[el * 68];
    *(uint4*)(row + 8 * p) =
        make_uint4(pk2(f0.x, f0.y), pk2(f0.z, f0.w), pk2(f1.x, f1.y), pk2(f1.z, f1.w));
    *(uint4*)(row + 8 * p + 4) =
        make_uint4(pk2(f2.x, f2.y), pk2(f2.z, f2.w), pk2(f3.x, f3.y), pk2(f3.z, f3.w));
    *(uint4*)(row + 32 + 8 * p) =
        make_uint4(pk2(m0.x, m0.y), pk2(m0.z, m0.w), pk2(m1.x, m1.y), pk2(m1.z, m1.w));
    *(uint4*)(row + 32 + 8 * p + 4) =
        make_uint4(pk2(m2.x, m2.y), pk2(m2.z, m2.w), pk2(m3.x, m3.y), pk2(m3.z, m3.w));
    __syncthreads();

    // ---- W fragments loaded AFTER phase 1 (barrier blocks hoist) -> short live
    // range, lower VGPR pressure during the latency-heavy gather phase ----
    short8 wf[4][4];
#pragma unroll
    for (int s = 0; s < 4; ++s)
#pragma unroll
        for (int t = 0; t < 4; ++t) {
            U4S8 cvt;
            cvt.u = wsW[(s * 4 + t) * 64 + lane];
            wf[s][t] = cvt.s;
        }
    float bv[4];
#pragma unroll
    for (int t = 0; t < 4; ++t) bv[t] = bias[16 * t + n];

    // ---- phase 2: wave w computes LDS rows [16w, 16w+16) x all 64 cols ----
    const int w = tid >> 6;
    floatx4 acc[4];
#pragma unroll
    for (int t = 0; t < 4; ++t) acc[t] = (floatx4){0.f, 0.f, 0.f, 0.f};
#pragma unroll
    for (int s = 0; s < 4; ++s) {
        U4S8 a;
        a.u = *(const uint4*)&lds_h[(16 * w + n) * 68 + 16 * s + 4 * q];
#pragma unroll
        for (int t = 0; t < 4; ++t)
            acc[t] = __builtin_amdgcn_mfma_f32_16x16x32_bf16(a.s, wf[s][t], acc[t], 0, 0, 0);
    }

    // ---- epilogue: C layout col=lane&15, row=4q+reg; map LDS row -> edge ----
#pragma unroll
    for (int r = 0; r < 4; ++r) {
        const int rowi = 16 * w + 4 * q + r;
        long long ee;
        if (paired) ee = (long long)g * 32 + (rowi & 31) + (long long)(rowi >> 5) * H;
        else        ee = (long long)g * 64 + rowi;
        if (ee < (long long)E) {
#pragma unroll
            for (int t = 0; t < 4; ++t) {
                float v = acc[t][r] + bv[t];
                out[(ee << 6) + 16 * t + n] = v > 0.f ? v : 0.f;
            }
        }
    }
}

extern "C" void kernel_launch(void* const* d_in, const int* in_sizes, int n_in,
                              void* d_out, int out_size, void* d_ws, size_t ws_size,
                              hipStream_t stream) {
    const float* feat = (const float*)d_in[0];
    const int*   esrc = (const int*)d_in[1];
    const int*   edst = (const int*)d_in[2];
    const float* W    = (const float*)d_in[5];
    const float* bias = (const float*)d_in[6];
    float* out = (float*)d_out;

    const int E  = in_sizes[1];
    const int NN = in_sizes[3];

    // workspace layout (16B aligned); dense index last so we can drop it if
    // the workspace is too small (fallback = revid flow)
    char* ws = (char*)d_ws;
    size_t o = 0;
    auto alloc = [&](size_t bytes) { void* p = ws + o; o = (o + bytes + 15) & ~(size_t)15; return p; };
    float* agg   = (float*)alloc((size_t)NN * 64 * sizeof(float));              // 10.24 MB
    int*   cnt   = (int*)alloc((size_t)NN * sizeof(int));                       // 160 KB (also cursor)
    int*   off   = (int*)alloc((size_t)(NN + 1) * sizeof(int));                 // 160 KB
    int*   csr   = (int*)alloc((size_t)E * sizeof(int));                        // 4 MB
    unsigned long long* tbl = (unsigned long long*)alloc((size_t)OA_SLOTS * 8); // 16 MB
    uint4* wsW   = (uint4*)alloc((size_t)16 * 64 * sizeof(uint4));              // 16 KB
    int*   revid = (int*)alloc((size_t)E * sizeof(int));                        // 4 MB
    const size_t dense_elems = (size_t)NN * GSZ;
    unsigned* dense = (unsigned*)alloc(dense_elems * sizeof(unsigned));         // 64 MB
    const int use_dense = (o <= ws_size) ? 1 : 0;

    hipMemsetAsync(cnt, 0, (size_t)NN * sizeof(int), stream);
    hipMemsetAsync(tbl, 0xFF, (size_t)OA_SLOTS * 8, stream);
    if (use_dense)
        hipMemsetAsync(dense, 0, dense_elems * sizeof(unsigned), stream);

    const int eb = (E + 255) / 256;
    wpack_kernel<<<1, 64, 0, stream>>>(W, wsW);
    prep_build_kernel<<<eb, 256, 0, stream>>>(esrc, edst, cnt, tbl,
                                              use_dense ? dense : nullptr, E, (unsigned)NN);
    scan_kernel<<<1, 1024, 0, stream>>>(cnt, off, NN, E);
    scatter_kernel<<<eb, 256, 0, stream>>>(edst, cnt, csr, E);
    if (!use_dense)
        mark_rev_kernel<<<eb, 256, 0, stream>>>(esrc, edst, tbl, revid, E, (unsigned)NN);
    agg_csr_kernel<<<(NN + 3) / 4, 256, 0, stream>>>(feat, csr, off, agg, NN);
    fused_kernel<<<(E + 63) / 64, 256, 0, stream>>>(
        feat, esrc, edst, agg, tbl, dense, revid, use_dense, wsW, bias, out, E, (unsigned)NN);
}

// Round 4
// 769.068 us; speedup vs baseline: 1.1771x; 1.1771x over previous
//
#include <hip/hip_runtime.h>
#include <cstdint>
#include <cstddef>

// ---------------- params ----------------
#define OA_LOG 21
static constexpr unsigned OA_SLOTS = 1u << OA_LOG;   // 2M slots x 8B = 16 MB (worst-case all-E insert)
static constexpr unsigned OA_MASK  = OA_SLOTS - 1;
static constexpr unsigned HASH_MUL = 2654435761u;    // Knuth multiplicative
static constexpr unsigned GSZ = 400;                 // within-graph key compressor; violations -> OA path
// rcode values
static constexpr unsigned char RC_ZERO   = 0;  // no reverse edge
static constexpr unsigned char RC_MIRROR = 1;  // unique reverse at e +/- E/2 (verified)
static constexpr unsigned char RC_PROBE  = 2;  // walk OA table (dups / cross / unmirrored)

typedef __attribute__((ext_vector_type(8))) short short8;   // 8 bf16 (4 VGPRs)
typedef __attribute__((ext_vector_type(4))) float floatx4;  // MFMA C/D

union U4S8 { uint4 u; short8 s; };

__device__ inline unsigned bf16rn(float x) {                // RNE f32->bf16
    unsigned u = __float_as_uint(x);
    return (u + 0x7FFFu + ((u >> 16) & 1u)) >> 16;
}
__device__ inline unsigned pk2(float a, float b) {
    return bf16rn(a) | (bf16rn(b) << 16);
}

// ---- pack W (128x64 f32, row-major) into 16 MFMA B-fragments of bf16 ----
__global__ void wpack_kernel(const float* __restrict__ W, uint4* __restrict__ wsW) {
    const int lane = threadIdx.x;   // 64 threads
    const int n = lane & 15, q = lane >> 4;
    for (int s = 0; s < 4; ++s)
        for (int t = 0; t < 4; ++t) {
            unsigned dw[4];
#pragma unroll
            for (int jj = 0; jj < 4; ++jj) {
                float a = W[(32 * s + 8 * q + 2 * jj) * 64 + 16 * t + n];
                float b = W[(32 * s + 8 * q + 2 * jj + 1) * 64 + 16 * t + n];
                dw[jj] = pk2(a, b);
            }
            wsW[(s * 4 + t) * 64 + lane] = make_uint4(dw[0], dw[1], dw[2], dw[3]);
        }
}

// ---- prep1: dst histogram + seen/dup bitmaps (all atomics L2-resident) ----
__global__ void prep1_kernel(const int* __restrict__ esrc,
                             const int* __restrict__ edst,
                             int* __restrict__ cnt,
                             unsigned* __restrict__ seen,
                             unsigned* __restrict__ dupb,
                             int E) {
    int e = blockIdx.x * blockDim.x + threadIdx.x;
    if (e >= E) return;
    const unsigned s = (unsigned)esrc[e], d = (unsigned)edst[e];
    atomicAdd(&cnt[d], 1);
    const unsigned gs = s / GSZ, gd = d / GSZ;
    if (gs == gd) {                       // within-graph: perfect key
        unsigned dk = s * GSZ + (d - gd * GSZ);      // < NN*GSZ
        unsigned w = dk >> 5, b = 1u << (dk & 31);
        unsigned old = atomicOr(&seen[w], b);
        if (old & b) atomicOr(&dupb[w], b);          // exact dup mark
    }
}

// one block, 1024 threads; exclusive offsets -> off[], cnt[] becomes scatter cursor
__global__ void scan_kernel(int* __restrict__ cnt, int* __restrict__ off, int NN, int E) {
    __shared__ int sd[1024];
    const int t = threadIdx.x;
    const int chunk = (NN + 1023) >> 10;
    const int lo = t * chunk, hi = min(lo + chunk, NN);
    int local = 0;
    for (int i = lo; i < hi; ++i) local += cnt[i];
    sd[t] = local;
    __syncthreads();
    for (int s = 1; s < 1024; s <<= 1) {
        int v = (t >= s) ? sd[t - s] : 0;
        __syncthreads();
        sd[t] += v;
        __syncthreads();
    }
    int run = sd[t] - local;  // exclusive base
    for (int i = lo; i < hi; ++i) {
        int c = cnt[i];
        off[i] = run;
        cnt[i] = run;   // cursor
        run += c;
    }
    if (t == 0) off[NN] = E;
}

// ---- prep2: CSR scatter + reverse classification (rcode) + selective OA insert.
// Insert rule (exact; proven complete): dup(key) || dup(rev) || !mirror_ok ||
// cross-graph || E odd. Classification: ZERO if rev key absent; MIRROR if rev
// unique and verified at e +/- H; else PROBE.
__global__ void prep2_kernel(const int* __restrict__ esrc,
                             const int* __restrict__ edst,
                             int* __restrict__ cursor,
                             int* __restrict__ csr,
                             const unsigned* __restrict__ seen,
                             const unsigned* __restrict__ dupb,
                             unsigned long long* __restrict__ tbl,
                             unsigned char* __restrict__ rcode,
                             int E, unsigned NN) {
    int e = blockIdx.x * blockDim.x + threadIdx.x;
    if (e >= E) return;
    const unsigned s = (unsigned)esrc[e], d = (unsigned)edst[e];
    int slot = atomicAdd(&cursor[d], 1);
    csr[slot] = e;

    const bool even = (E & 1) == 0;
    const int H = E >> 1;
    bool ins;
    unsigned char code;
    const unsigned gs = s / GSZ, gd = d / GSZ;
    if (even && gs == gd) {
        const int m = (e < H) ? e + H : e - H;
        const unsigned sm = (unsigned)esrc[m], dm = (unsigned)edst[m];
        const bool mok = (sm == d) && (dm == s);     // key(m) == rev(e), verified
        const unsigned dk = s * GSZ + (d - gd * GSZ);
        const unsigned rk = d * GSZ + (s - gs * GSZ);
        const bool dupK  = (dupb[dk >> 5] >> (dk & 31)) & 1u;
        const bool seenR = (seen[rk >> 5] >> (rk & 31)) & 1u;
        const bool dupR  = (dupb[rk >> 5] >> (rk & 31)) & 1u;
        ins  = dupK || dupR || !mok;
        code = !seenR ? RC_ZERO : (dupR ? RC_PROBE : (mok ? RC_MIRROR : RC_PROBE));
    } else {
        ins = true;                                  // odd E or cross-graph: full generality
        code = RC_PROBE;
    }
    rcode[e] = code;

    if (ins) {
        const unsigned k = s * NN + d;               // global key, < 2^31; never sentinel
        unsigned long long mine =
            ((unsigned long long)(unsigned)e << 32) | (unsigned long long)k;
        unsigned sl = (k * HASH_MUL) >> (32 - OA_LOG);
        const unsigned long long EMPTY = ~0ull;
        while (atomicCAS(&tbl[sl], EMPTY, mine) != EMPTY)
            sl = (sl + 1) & OA_MASK;
    }
}

// ---- agg via CSR: one wave per node, lane = column; 8-deep load pipelining ----
__global__ __launch_bounds__(256)
void agg_csr_kernel(const float* __restrict__ feat, const int* __restrict__ csr,
                    const int* __restrict__ off, float* __restrict__ agg, int NN) {
    const int wid = (blockIdx.x * blockDim.x + threadIdx.x) >> 6;
    const int lane = threadIdx.x & 63;
    if (wid >= NN) return;
    const int i0 = off[wid], i1 = off[wid + 1];
    float acc = 0.f;
    int i = i0;
    for (; i + 8 <= i1; i += 8) {
        int c[8];
#pragma unroll
        for (int j = 0; j < 8; ++j) c[j] = csr[i + j];
        float a[8];
#pragma unroll
        for (int j = 0; j < 8; ++j) a[j] = feat[((long long)c[j] << 6) + lane];
        acc += ((a[0] + a[1]) + (a[2] + a[3])) + ((a[4] + a[5]) + (a[6] + a[7]));
    }
    for (; i < i1; ++i) acc += feat[((long long)csr[i] << 6) + lane];
    agg[((long long)wid << 6) + lane] = acc;
}

// ---- fused: h = [feat, agg[src]-revsum] (bf16, LDS) ; out = relu(h@W + b) via MFMA ----
__global__ __launch_bounds__(256, 4)
void fused_kernel(const float* __restrict__ feat,
                  const int* __restrict__ esrc,
                  const int* __restrict__ edst,
                  const float* __restrict__ agg,
                  const unsigned long long* __restrict__ tbl,
                  const unsigned char* __restrict__ rcode,
                  const uint4* __restrict__ wsW,
                  const float* __restrict__ bias,
                  float* __restrict__ out,
                  int E, unsigned NN) {
    // 64 edge rows x 128 bf16 cols, padded to 68 dwords/row
    __shared__ unsigned lds_h[64 * 68];
    const int tid = threadIdx.x;
    const int lane = tid & 63;
    const int n = lane & 15;
    const int q = lane >> 4;
    const int g = blockIdx.x;
    const long long H = (long long)(E >> 1);
    const bool paired = (E & 63) == 0;

    // ---- phase 1: 4 threads/edge, 16 cols each ----
    const int el = tid >> 2;     // LDS row 0..63
    const int p = tid & 3;
    long long e;
    if (paired) e = (long long)g * 32 + (el & 31) + (long long)(el >> 5) * H;
    else        e = (long long)g * 64 + el;

    float4 f0, f1, f2, f3, m0, m1, m2, m3;
    if (e < (long long)E) {
        const float4* fp = (const float4*)(feat + (e << 6) + 16 * p);
        f0 = fp[0]; f1 = fp[1]; f2 = fp[2]; f3 = fp[3];
        const int s_ = esrc[e], d_ = edst[e];
        const float4* ap = (const float4*)(agg + ((long long)s_ << 6) + 16 * p);
        m0 = ap[0]; m1 = ap[1]; m2 = ap[2]; m3 = ap[3];

        const unsigned char code = rcode[e];
        float4 r0, r1, r2, r3;
        r0 = r1 = r2 = r3 = make_float4(0.f, 0.f, 0.f, 0.f);
        if (code == RC_MIRROR) {
            // verified unique reverse at e +/- H; L1-hot under paired layout
            const long long m = (e < H) ? e + H : e - H;
            const float4* rp = (const float4*)(feat + (m << 6) + 16 * p);
            r0 = rp[0]; r1 = rp[1]; r2 = rp[2]; r3 = rp[3];
        } else if (code == RC_PROBE) {
            // OA walk, sum ALL matches (multi-edges / cross-graph); 0 if none
            const unsigned rk = (unsigned)d_ * NN + (unsigned)s_;
            unsigned slot = (rk * HASH_MUL) >> (32 - OA_LOG);
            while (true) {
                unsigned long long v = tbl[slot];
                if ((unsigned)v == 0xFFFFFFFFu) break;
                if ((unsigned)v == rk) {
                    const float4* rp =
                        (const float4*)(feat + ((long long)(v >> 32) << 6) + 16 * p);
                    float4 a0 = rp[0], a1 = rp[1], a2 = rp[2], a3 = rp[3];
                    r0.x += a0.x; r0.y += a0.y; r0.z += a0.z; r0.w += a0.w;
                    r1.x += a1.x; r1.y += a1.y; r1.z += a1.z; r1.w += a1.w;
                    r2.x += a2.x; r2.y += a2.y; r2.z += a2.z; r2.w += a2.w;
                    r3.x += a3.x; r3.y += a3.y; r3.z += a3.z; r3.w += a3.w;
                }
                slot = (slot + 1) & OA_MASK;
            }
        }
        m0.x -= r0.x; m0.y -= r0.y; m0.z -= r0.z; m0.w -= r0.w;
        m1.x -= r1.x; m1.y -= r1.y; m1.z -= r1.z; m1.w -= r1.w;
        m2.x -= r2.x; m2.y -= r2.y; m2.z -= r2.z; m2.w -= r2.w;
        m3.x -= r3.x; m3.y -= r3.y; m3.z -= r3.z; m3.w -= r3.w;
    } else {
        f0 = f1 = f2 = f3 = make_float4(0.f, 0.f, 0.f, 0.f);
        m0 = m1 = m2 = m3 = make_float4(0.f, 0.f, 0.f, 0.f);
    }
    unsigned* row = &lds_h[el * 68];
    *(uint4*)(row + 8 * p) =
        make_uint4(pk2(f0.x, f0.y), pk2(f0.z, f0.w), pk2(f1.x, f1.y), pk2(f1.z, f1.w));
    *(uint4*)(row + 8 * p + 4) =
        make_uint4(pk2(f2.x, f2.y), pk2(f2.z, f2.w), pk2(f3.x, f3.y), pk2(f3.z, f3.w));
    *(uint4*)(row + 32 + 8 * p) =
        make_uint4(pk2(m0.x, m0.y), pk2(m0.z, m0.w), pk2(m1.x, m1.y), pk2(m1.z, m1.w));
    *(uint4*)(row + 32 + 8 * p + 4) =
        make_uint4(pk2(m2.x, m2.y), pk2(m2.z, m2.w), pk2(m3.x, m3.y), pk2(m3.z, m3.w));
    __syncthreads();

    // ---- W fragments loaded AFTER phase 1 (barrier blocks hoist) ----
    short8 wf[4][4];
#pragma unroll
    for (int s = 0; s < 4; ++s)
#pragma unroll
        for (int t = 0; t < 4; ++t) {
            U4S8 cvt;
            cvt.u = wsW[(s * 4 + t) * 64 + lane];
            wf[s][t] = cvt.s;
        }
    float bv[4];
#pragma unroll
    for (int t = 0; t < 4; ++t) bv[t] = bias[16 * t + n];

    // ---- phase 2: wave w computes LDS rows [16w, 16w+16) x all 64 cols ----
    const int w = tid >> 6;
    floatx4 acc[4];
#pragma unroll
    for (int t = 0; t < 4; ++t) acc[t] = (floatx4){0.f, 0.f, 0.f, 0.f};
#pragma unroll
    for (int s = 0; s < 4; ++s) {
        U4S8 a;
        a.u = *(const uint4*)&lds_h[(16 * w + n) * 68 + 16 * s + 4 * q];
#pragma unroll
        for (int t = 0; t < 4; ++t)
            acc[t] = __builtin_amdgcn_mfma_f32_16x16x32_bf16(a.s, wf[s][t], acc[t], 0, 0, 0);
    }

    // ---- epilogue: C layout col=lane&15, row=4q+reg; map LDS row -> edge ----
#pragma unroll
    for (int r = 0; r < 4; ++r) {
        const int rowi = 16 * w + 4 * q + r;
        long long ee;
        if (paired) ee = (long long)g * 32 + (rowi & 31) + (long long)(rowi >> 5) * H;
        else        ee = (long long)g * 64 + rowi;
        if (ee < (long long)E) {
#pragma unroll
            for (int t = 0; t < 4; ++t) {
                float v = acc[t][r] + bv[t];
                out[(ee << 6) + 16 * t + n] = v > 0.f ? v : 0.f;
            }
        }
    }
}

extern "C" void kernel_launch(void* const* d_in, const int* in_sizes, int n_in,
                              void* d_out, int out_size, void* d_ws, size_t ws_size,
                              hipStream_t stream) {
    const float* feat = (const float*)d_in[0];
    const int*   esrc = (const int*)d_in[1];
    const int*   edst = (const int*)d_in[2];
    const float* W    = (const float*)d_in[5];
    const float* bias = (const float*)d_in[6];
    float* out = (float*)d_out;

    const int E  = in_sizes[1];
    const int NN = in_sizes[3];

    // workspace layout (16B aligned) — total ~36 MB
    char* ws = (char*)d_ws;
    size_t o = 0;
    auto alloc = [&](size_t bytes) { void* p = ws + o; o = (o + bytes + 15) & ~(size_t)15; return p; };
    float* agg   = (float*)alloc((size_t)NN * 64 * sizeof(float));              // 10.24 MB
    int*   cnt   = (int*)alloc((size_t)NN * sizeof(int));                       // 160 KB (also cursor)
    int*   off   = (int*)alloc((size_t)(NN + 1) * sizeof(int));                 // 160 KB
    int*   csr   = (int*)alloc((size_t)E * sizeof(int));                        // 4 MB
    unsigned long long* tbl = (unsigned long long*)alloc((size_t)OA_SLOTS * 8); // 16 MB
    uint4* wsW   = (uint4*)alloc((size_t)16 * 64 * sizeof(uint4));              // 16 KB
    const size_t bm_words = ((size_t)NN * GSZ + 31) / 32;                       // 512K words
    unsigned* seen = (unsigned*)alloc(bm_words * sizeof(unsigned));             // 2 MB
    unsigned* dupb = (unsigned*)alloc(bm_words * sizeof(unsigned));             // 2 MB
    unsigned char* rcode = (unsigned char*)alloc((size_t)E);                    // 1 MB

    hipMemsetAsync(cnt, 0, (size_t)NN * sizeof(int), stream);
    hipMemsetAsync(tbl, 0xFF, (size_t)OA_SLOTS * 8, stream);
    hipMemsetAsync(seen, 0, 2 * bm_words * sizeof(unsigned), stream);  // seen+dupb contiguous

    const int eb = (E + 255) / 256;
    wpack_kernel<<<1, 64, 0, stream>>>(W, wsW);
    prep1_kernel<<<eb, 256, 0, stream>>>(esrc, edst, cnt, seen, dupb, E);
    scan_kernel<<<1, 1024, 0, stream>>>(cnt, off, NN, E);
    prep2_kernel<<<eb, 256, 0, stream>>>(esrc, edst, cnt, csr, seen, dupb, tbl,
                                         rcode, E, (unsigned)NN);
    agg_csr_kernel<<<(NN + 3) / 4, 256, 0, stream>>>(feat, csr, off, agg, NN);
    fused_kernel<<<(E + 63) / 64, 256, 0, stream>>>(
        feat, esrc, edst, agg, tbl, rcode, wsW, bias, out, E, (unsigned)NN);
}